// Round 1
// baseline (4405.733 us; speedup 1.0000x reference)
//
#include <hip/hip_runtime.h>
#include <math.h>

#define B 4
#define T 4096
#define D 256
#define NCH 16
#define CHT (T / NCH)

// ---------------------------------------------------------------------------
// Stage 1a: partial sums for instance-norm stats (per (tensor, b, t-chunk)).
// Each block: 256 threads = one channel each, 256 t's, coalesced reads.
// ---------------------------------------------------------------------------
__global__ __launch_bounds__(256) void k_stats_part(
    const float* __restrict__ fc, const float* __restrict__ fs,
    const float* __restrict__ fcs, float* __restrict__ part)
{
    int blk = blockIdx.x;                 // 3*B*NCH
    int tensor = blk / (B * NCH);
    int rem = blk % (B * NCH);
    int b = rem / NCH, ch = rem % NCH;
    const float* x = (tensor == 0) ? fc : ((tensor == 1) ? fs : fcs);
    int c = threadIdx.x;
    const float* p = x + ((size_t)b * T + (size_t)ch * CHT) * D + c;
    float s = 0.f, ss = 0.f;
    for (int t = 0; t < CHT; ++t) {
        float v = p[(size_t)t * D];
        s += v; ss += v * v;
    }
    float* o = part + (((size_t)tensor * B + b) * NCH + ch) * 2 * D;
    o[c] = s;
    o[D + c] = ss;
}

// ---------------------------------------------------------------------------
// Stage 1b: finalize mean / rstd.  stats layout: per tensor: mean[B][D] then
// rstd[B][D]  (tensor stride 2*B*D floats).
// ---------------------------------------------------------------------------
__global__ __launch_bounds__(256) void k_stats_final(
    const float* __restrict__ part, float* __restrict__ stats)
{
    int blk = blockIdx.x;                 // 3*B
    int tensor = blk / B, b = blk % B;
    int c = threadIdx.x;
    const float* pp = part + (((size_t)tensor * B + b) * NCH) * 2 * D;
    float s = 0.f, ss = 0.f;
    for (int ch = 0; ch < NCH; ++ch) {
        s  += pp[(size_t)ch * 2 * D + c];
        ss += pp[(size_t)ch * 2 * D + D + c];
    }
    float mean = s / (float)T;
    float var  = ss / (float)T - mean * mean;   // biased (matches jnp.var)
    float rstd = rsqrtf(var + 1e-5f);
    float* st = stats + (size_t)tensor * 2 * B * D;
    st[(size_t)b * D + c]          = mean;
    st[(size_t)B * D + b * D + c]  = rstd;
}

// ---------------------------------------------------------------------------
// Stage 2: per-token linear (1x1 conv):  out[t][o] = sum_c W[o][c]*xn[t][c]+bias[o]
// xn = (x-mean)*rstd when use_norm.  64 tokens/block, o = tid, acc[64] in regs.
// LDS X-tile read is same-address broadcast per (m,c4) -> conflict-free.
// ---------------------------------------------------------------------------
__global__ __launch_bounds__(256) void k_gemm(
    const float* __restrict__ x, const float* __restrict__ W,
    const float* __restrict__ bias, const float* __restrict__ stats,
    float* __restrict__ out, int use_norm)
{
    __shared__ float Xl[64][256];
    int m0 = blockIdx.x * 64;             // global token (b*T flat)
    int b  = m0 / T;
    int tid = threadIdx.x;
    const float* mean = stats;
    const float* rstd = stats + B * D;

    // stage + normalize 64x256 tile, vectorized float4
    #pragma unroll
    for (int j = 0; j < 16; ++j) {
        int idx = tid + j * 256;          // float4 index, 0..4095
        int m = idx >> 6, c4 = idx & 63;
        float4 v = *(const float4*)(x + ((size_t)(m0 + m)) * D + c4 * 4);
        if (use_norm) {
            int c = c4 * 4;
            v.x = (v.x - mean[(size_t)b * D + c + 0]) * rstd[(size_t)b * D + c + 0];
            v.y = (v.y - mean[(size_t)b * D + c + 1]) * rstd[(size_t)b * D + c + 1];
            v.z = (v.z - mean[(size_t)b * D + c + 2]) * rstd[(size_t)b * D + c + 2];
            v.w = (v.w - mean[(size_t)b * D + c + 3]) * rstd[(size_t)b * D + c + 3];
        }
        *(float4*)&Xl[m][c4 * 4] = v;
    }
    __syncthreads();

    int o = tid;
    float acc[64];
    float bo = bias[o];
    #pragma unroll
    for (int m = 0; m < 64; ++m) acc[m] = bo;

    const float4* W4 = (const float4*)(W + (size_t)o * D);
    for (int c4 = 0; c4 < 64; ++c4) {
        float4 wv = W4[c4];
        #pragma unroll
        for (int m = 0; m < 64; ++m) {
            float4 xv = *(const float4*)&Xl[m][c4 * 4];
            acc[m] = fmaf(wv.x, xv.x, fmaf(wv.y, xv.y, fmaf(wv.z, xv.z, fmaf(wv.w, xv.w, acc[m]))));
        }
    }
    #pragma unroll
    for (int m = 0; m < 64; ++m)
        out[((size_t)(m0 + m)) * D + o] = acc[m];
}

// ---------------------------------------------------------------------------
// Stage 3: flash attention with dual accumulators (A*V, A*V^2) + fused
// epilogue  out = sqrt(max(E2-M^2,1e-6)) * inorm(fcs) + M.
// TQ=32 q/block, KC=32 k/chunk. thread = (q_local = tid>>3, seg = tid&7).
// ---------------------------------------------------------------------------
__global__ __launch_bounds__(256) void k_attn(
    const float* __restrict__ Q, const float* __restrict__ K,
    const float* __restrict__ V, const float* __restrict__ fcs,
    const float* __restrict__ stats_fcs, float* __restrict__ out)
{
    __shared__ float Kl[32][256];
    __shared__ float Vl[32][256];
    __shared__ float P[32][33];
    __shared__ float mrun[32], lrun[32], corr_s[32];

    int blk = blockIdx.x;                 // B * (T/32)
    int b  = blk / (T / 32);
    int q0 = (blk % (T / 32)) * 32;
    int tid = threadIdx.x;
    int ql = tid >> 3;                    // 0..31
    int seg = tid & 7;                    // 0..7  (d-range seg*32..seg*32+31)

    size_t qrow = ((size_t)b * T + q0 + ql) * D + seg * 32;
    float4 Qr[8];
    #pragma unroll
    for (int j = 0; j < 8; ++j) Qr[j] = *(const float4*)(Q + qrow + j * 4);

    float4 accM[8], accE[8];
    #pragma unroll
    for (int j = 0; j < 8; ++j) {
        accM[j] = make_float4(0.f, 0.f, 0.f, 0.f);
        accE[j] = make_float4(0.f, 0.f, 0.f, 0.f);
    }
    if (tid < 32) { mrun[tid] = -1e30f; lrun[tid] = 0.f; }

    const float* Kb = K + (size_t)b * T * D;
    const float* Vb = V + (size_t)b * T * D;

    for (int k0 = 0; k0 < T; k0 += 32) {
        __syncthreads();                  // Kl/Vl free + init visible
        // ---- stage K,V chunk (coalesced float4) ----
        #pragma unroll
        for (int j = 0; j < 8; ++j) {
            int idx = tid + j * 256;      // float4 index 0..2047
            int row = idx >> 6, c4 = idx & 63;
            *(float4*)&Kl[row][c4 * 4] = *(const float4*)(Kb + ((size_t)(k0 + row)) * D + c4 * 4);
            *(float4*)&Vl[row][c4 * 4] = *(const float4*)(Vb + ((size_t)(k0 + row)) * D + c4 * 4);
        }
        __syncthreads();
        // ---- logits: partial dot over own 32-wide segment, 8-lane butterfly ----
        for (int k = 0; k < 32; ++k) {
            float s = 0.f;
            #pragma unroll
            for (int j = 0; j < 8; ++j) {
                float4 kv = *(const float4*)&Kl[k][seg * 32 + j * 4];
                s = fmaf(Qr[j].x, kv.x, fmaf(Qr[j].y, kv.y, fmaf(Qr[j].z, kv.z, fmaf(Qr[j].w, kv.w, s))));
            }
            s += __shfl_xor(s, 1);
            s += __shfl_xor(s, 2);
            s += __shfl_xor(s, 4);
            if (seg == 0) P[ql][k] = s;   // no 1/sqrt(d): reference has none
        }
        __syncthreads();
        // ---- online softmax bookkeeping (32 threads, one per q) ----
        if (tid < 32) {
            int q = tid;
            float cm = -1e30f;
            for (int k = 0; k < 32; ++k) cm = fmaxf(cm, P[q][k]);
            float m_old = mrun[q];
            float m_new = fmaxf(m_old, cm);
            float corr = __expf(m_old - m_new);
            float psum = 0.f;
            for (int k = 0; k < 32; ++k) {
                float p = __expf(P[q][k] - m_new);
                P[q][k] = p;
                psum += p;
            }
            lrun[q] = lrun[q] * corr + psum;
            mrun[q] = m_new;
            corr_s[q] = corr;
        }
        __syncthreads();
        // ---- rescale + accumulate M and E2 ----
        float corr = corr_s[ql];
        #pragma unroll
        for (int j = 0; j < 8; ++j) {
            accM[j].x *= corr; accM[j].y *= corr; accM[j].z *= corr; accM[j].w *= corr;
            accE[j].x *= corr; accE[j].y *= corr; accE[j].z *= corr; accE[j].w *= corr;
        }
        for (int k = 0; k < 32; ++k) {
            float w = P[ql][k];
            #pragma unroll
            for (int j = 0; j < 8; ++j) {
                float4 vv = *(const float4*)&Vl[k][seg * 32 + j * 4];
                float tx = w * vv.x, ty = w * vv.y, tz = w * vv.z, tw = w * vv.w;
                accM[j].x += tx; accM[j].y += ty; accM[j].z += tz; accM[j].w += tw;
                accE[j].x = fmaf(tx, vv.x, accE[j].x);
                accE[j].y = fmaf(ty, vv.y, accE[j].y);
                accE[j].z = fmaf(tz, vv.z, accE[j].z);
                accE[j].w = fmaf(tw, vv.w, accE[j].w);
            }
        }
    }

    // ---- epilogue ----
    float linv = 1.f / lrun[ql];
    const float* mfc = stats_fcs;
    const float* rfc = stats_fcs + B * D;
    size_t orow = ((size_t)b * T + q0 + ql) * D + seg * 32;
    #pragma unroll
    for (int j = 0; j < 8; ++j) {
        int c = seg * 32 + j * 4;
        float4 fv = *(const float4*)(fcs + orow + j * 4);
        float4 res;
        float Mx = accM[j].x * linv, Ex = accE[j].x * linv;
        float My = accM[j].y * linv, Ey = accE[j].y * linv;
        float Mz = accM[j].z * linv, Ez = accE[j].z * linv;
        float Mw = accM[j].w * linv, Ew = accE[j].w * linv;
        res.x = sqrtf(fmaxf(Ex - Mx * Mx, 1e-6f)) * ((fv.x - mfc[(size_t)b * D + c + 0]) * rfc[(size_t)b * D + c + 0]) + Mx;
        res.y = sqrtf(fmaxf(Ey - My * My, 1e-6f)) * ((fv.y - mfc[(size_t)b * D + c + 1]) * rfc[(size_t)b * D + c + 1]) + My;
        res.z = sqrtf(fmaxf(Ez - Mz * Mz, 1e-6f)) * ((fv.z - mfc[(size_t)b * D + c + 2]) * rfc[(size_t)b * D + c + 2]) + Mz;
        res.w = sqrtf(fmaxf(Ew - Mw * Mw, 1e-6f)) * ((fv.w - mfc[(size_t)b * D + c + 3]) * rfc[(size_t)b * D + c + 3]) + Mw;
        *(float4*)(out + orow + j * 4) = res;
    }
}

// ---------------------------------------------------------------------------
extern "C" void kernel_launch(void* const* d_in, const int* in_sizes, int n_in,
                              void* d_out, int out_size, void* d_ws, size_t ws_size,
                              hipStream_t stream)
{
    const float* fc  = (const float*)d_in[0];
    const float* fs  = (const float*)d_in[1];
    const float* fcs = (const float*)d_in[2];
    const float* Wf  = (const float*)d_in[3];
    const float* bf  = (const float*)d_in[4];
    const float* Wg  = (const float*)d_in[5];
    const float* bg  = (const float*)d_in[6];
    const float* Wh  = (const float*)d_in[7];
    const float* bh  = (const float*)d_in[8];
    float* out = (float*)d_out;

    char* ws = (char*)d_ws;
    float* stats = (float*)ws;                       // 3*2*B*D = 6144 floats
    float* part  = (float*)(ws + (64 << 10));        // 3*B*NCH*2*D = 98304 floats
    float* Q  = (float*)(ws + (1 << 20));            // B*T*D each = 16 MB
    float* Kt = Q  + (size_t)B * T * D;
    float* Vt = Kt + (size_t)B * T * D;

    k_stats_part<<<3 * B * NCH, 256, 0, stream>>>(fc, fs, fcs, part);
    k_stats_final<<<3 * B, 256, 0, stream>>>(part, stats);

    float* st_fc  = stats + 0 * 2 * B * D;
    float* st_fs  = stats + 1 * 2 * B * D;
    float* st_fcs = stats + 2 * 2 * B * D;

    k_gemm<<<(B * T) / 64, 256, 0, stream>>>(fc, Wf, bf, st_fc, Q,  1);
    k_gemm<<<(B * T) / 64, 256, 0, stream>>>(fs, Wg, bg, st_fs, Kt, 1);
    k_gemm<<<(B * T) / 64, 256, 0, stream>>>(fs, Wh, bh, st_fs, Vt, 0);

    k_attn<<<B * (T / 32), 256, 0, stream>>>(Q, Kt, Vt, fcs, st_fcs, out);
}

// Round 3
// 777.159 us; speedup vs baseline: 5.6690x; 5.6690x over previous
//
#include <hip/hip_runtime.h>
#include <math.h>

#define B 4
#define T 4096
#define D 256
#define NCH 16
#define CHT (T / NCH)
#define KC 32
#define NCHUNK (T / KC)

typedef __attribute__((ext_vector_type(8))) _Float16 half8;
typedef __attribute__((ext_vector_type(4))) float f32x4;

// ---------------------------------------------------------------------------
// Stage 1a: partial sums for instance-norm stats.
// ---------------------------------------------------------------------------
__global__ __launch_bounds__(256) void k_stats_part(
    const float* __restrict__ fc, const float* __restrict__ fs,
    const float* __restrict__ fcs, float* __restrict__ part)
{
    int blk = blockIdx.x;                 // 3*B*NCH
    int tensor = blk / (B * NCH);
    int rem = blk % (B * NCH);
    int b = rem / NCH, ch = rem % NCH;
    const float* x = (tensor == 0) ? fc : ((tensor == 1) ? fs : fcs);
    int c = threadIdx.x;
    const float* p = x + ((size_t)b * T + (size_t)ch * CHT) * D + c;
    float s = 0.f, ss = 0.f;
    for (int t = 0; t < CHT; ++t) {
        float v = p[(size_t)t * D];
        s += v; ss += v * v;
    }
    float* o = part + (((size_t)tensor * B + b) * NCH + ch) * 2 * D;
    o[c] = s;
    o[D + c] = ss;
}

// ---------------------------------------------------------------------------
// Stage 1b: finalize mean / rstd.
// ---------------------------------------------------------------------------
__global__ __launch_bounds__(256) void k_stats_final(
    const float* __restrict__ part, float* __restrict__ stats)
{
    int blk = blockIdx.x;                 // 3*B
    int tensor = blk / B, b = blk % B;
    int c = threadIdx.x;
    const float* pp = part + (((size_t)tensor * B + b) * NCH) * 2 * D;
    float s = 0.f, ss = 0.f;
    for (int ch = 0; ch < NCH; ++ch) {
        s  += pp[(size_t)ch * 2 * D + c];
        ss += pp[(size_t)ch * 2 * D + D + c];
    }
    float mean = s / (float)T;
    float var  = ss / (float)T - mean * mean;
    float rstd = rsqrtf(var + 1e-5f);
    float* st = stats + (size_t)tensor * 2 * B * D;
    st[(size_t)b * D + c]          = mean;
    st[(size_t)B * D + b * D + c]  = rstd;
}

// ---------------------------------------------------------------------------
// Stage 2: per-token linear. mode 1: fp16 row-major [b*T][D]. mode 2: fp16
// transposed [b][D][T] (for V, so attention PV B-frags are contiguous).
// ---------------------------------------------------------------------------
__global__ __launch_bounds__(256) void k_gemm(
    const float* __restrict__ x, const float* __restrict__ W,
    const float* __restrict__ bias, const float* __restrict__ stats,
    _Float16* __restrict__ outh, int use_norm, int mode)
{
    __shared__ float Xl[64][256];
    int m0 = blockIdx.x * 64;
    int b  = m0 / T;
    int tid = threadIdx.x;
    const float* mean = stats;
    const float* rstd = stats + B * D;

    #pragma unroll
    for (int j = 0; j < 16; ++j) {
        int idx = tid + j * 256;
        int m = idx >> 6, c4 = idx & 63;
        float4 v = *(const float4*)(x + ((size_t)(m0 + m)) * D + c4 * 4);
        if (use_norm) {
            int c = c4 * 4;
            v.x = (v.x - mean[(size_t)b * D + c + 0]) * rstd[(size_t)b * D + c + 0];
            v.y = (v.y - mean[(size_t)b * D + c + 1]) * rstd[(size_t)b * D + c + 1];
            v.z = (v.z - mean[(size_t)b * D + c + 2]) * rstd[(size_t)b * D + c + 2];
            v.w = (v.w - mean[(size_t)b * D + c + 3]) * rstd[(size_t)b * D + c + 3];
        }
        *(float4*)&Xl[m][c4 * 4] = v;
    }
    __syncthreads();

    int o = tid;
    float acc[64];
    float bo = bias[o];
    #pragma unroll
    for (int m = 0; m < 64; ++m) acc[m] = bo;

    const float4* W4 = (const float4*)(W + (size_t)o * D);
    for (int c4 = 0; c4 < 64; ++c4) {
        float4 wv = W4[c4];
        #pragma unroll
        for (int m = 0; m < 64; ++m) {
            float4 xv = *(const float4*)&Xl[m][c4 * 4];
            acc[m] = fmaf(wv.x, xv.x, fmaf(wv.y, xv.y, fmaf(wv.z, xv.z, fmaf(wv.w, xv.w, acc[m]))));
        }
    }

    if (mode == 1) {
        #pragma unroll
        for (int m = 0; m < 64; ++m)
            outh[((size_t)(m0 + m)) * D + o] = (_Float16)acc[m];
    } else {
        int bb = m0 / T, t0 = m0 % T;
        _Float16 tmp[64];
        #pragma unroll
        for (int m = 0; m < 64; ++m) tmp[m] = (_Float16)acc[m];
        _Float16* dst = outh + ((size_t)(bb * D + o)) * T + t0;
        #pragma unroll
        for (int g = 0; g < 8; ++g)
            *(half8*)(dst + g * 8) = *(half8*)&tmp[g * 8];
    }
}

// ---------------------------------------------------------------------------
// Stage 3: fp16 MFMA flash attention, dual accumulators (M = A·v̂,
// E2 = A·V2hi + A·V2lo with V2hi+V2lo == v̂² exactly), fused epilogue.
// 4 waves, TQ=64 (wave w owns q rows 16w..16w+15), KC=32.
// ---------------------------------------------------------------------------
__global__ __launch_bounds__(256, 1) void k_attn(
    const _Float16* __restrict__ Qg, const _Float16* __restrict__ Kg,
    const _Float16* __restrict__ Vtg, const float* __restrict__ fcs,
    const float* __restrict__ stats_fcs, float* __restrict__ out)
{
    __shared__ __align__(16) _Float16 Kl[32 * 256];   // [key][d], XOR swizzled
    __shared__ __align__(16) _Float16 Vh[256 * 32];   // [d][key], XOR swizzled
    __shared__ __align__(16) _Float16 V2h[256 * 32];
    __shared__ __align__(16) _Float16 V2l[256 * 32];
    __shared__ __align__(16) _Float16 Pl[64 * 32];    // [q][key], XOR swizzled

    const int tid = threadIdx.x;
    const int l = tid & 63;
    const int w = tid >> 6;
    const int b  = blockIdx.x >> 6;
    const int q0 = (blockIdx.x & 63) << 6;
    const int lo16 = l & 15, hi4 = l >> 4;

    // Q fragments: A[m=lo16][k=hi4*8+e], d-chunk kk
    half8 qf[8];
    {
        const _Float16* qp = Qg + ((size_t)(b * T + q0 + 16 * w + lo16)) * D + hi4 * 8;
        #pragma unroll
        for (int kk = 0; kk < 8; ++kk) qf[kk] = *(const half8*)(qp + kk * 32);
    }

    f32x4 accM[16], accE[16];
    #pragma unroll
    for (int j = 0; j < 16; ++j) {
        accM[j] = (f32x4){0.f, 0.f, 0.f, 0.f};
        accE[j] = (f32x4){0.f, 0.f, 0.f, 0.f};
    }
    float m_run[4] = {-1e30f, -1e30f, -1e30f, -1e30f};
    float l_run[4] = {0.f, 0.f, 0.f, 0.f};

    const _Float16* KgB = Kg + (size_t)b * T * D;
    const _Float16* VtB = Vtg + (size_t)b * D * T;

    half8 kreg[4], vreg[4];

    auto issue = [&](int kc) {
        int k0 = kc * KC;
        #pragma unroll
        for (int i = 0; i < 4; ++i) {
            int g = tid + i * 256;                    // row=g>>5, cg=g&31
            kreg[i] = *(const half8*)(KgB + (size_t)(k0 + (g >> 5)) * D + (g & 31) * 8);
        }
        #pragma unroll
        for (int i = 0; i < 4; ++i) {
            int g = tid + i * 256;                    // d=g>>2, kg=g&3
            vreg[i] = *(const half8*)(VtB + (size_t)(g >> 2) * T + k0 + (g & 3) * 8);
        }
    };
    auto commit = [&]() {
        #pragma unroll
        for (int i = 0; i < 4; ++i) {
            int g = tid + i * 256; int row = g >> 5, cg = g & 31;
            *(half8*)&Kl[row * 256 + ((cg ^ (row & 7)) << 3)] = kreg[i];
        }
        #pragma unroll
        for (int i = 0; i < 4; ++i) {
            int g = tid + i * 256; int d = g >> 2, kg = g & 3;
            int p = d * 32 + ((kg ^ ((d >> 1) & 3)) << 3);
            *(half8*)&Vh[p] = vreg[i];
            _Float16 h8[8], l8[8];
            #pragma unroll
            for (int e = 0; e < 8; ++e) {
                float f  = (float)vreg[i][e];
                float f2 = f * f;                      // exact in fp32 (11-bit mantissa in)
                _Float16 h = (_Float16)f2;
                float fl = f2 - (float)h;              // residual, fits fp16 (exact to 22 bits)
                h8[e] = h; l8[e] = (_Float16)fl;
            }
            *(half8*)&V2h[p] = *(half8*)h8;
            *(half8*)&V2l[p] = *(half8*)l8;
        }
    };

    issue(0); commit(); __syncthreads();

    for (int kc = 0; kc < NCHUNK; ++kc) {
        if (kc + 1 < NCHUNK) issue(kc + 1);   // T14: loads fly under compute

        // ---- QK^T: S[16q x 32key] as two 16x16 C-frags ----
        f32x4 c0 = (f32x4){0.f, 0.f, 0.f, 0.f}, c1 = (f32x4){0.f, 0.f, 0.f, 0.f};
        #pragma unroll
        for (int kk = 0; kk < 8; ++kk) {
            int cg = kk * 4 + hi4;
            half8 b0 = *(const half8*)&Kl[lo16 * 256 + ((cg ^ (lo16 & 7)) << 3)];
            half8 b1 = *(const half8*)&Kl[(16 + lo16) * 256 + ((cg ^ ((16 + lo16) & 7)) << 3)];
            c0 = __builtin_amdgcn_mfma_f32_16x16x32_f16(qf[kk], b0, c0, 0, 0, 0);
            c1 = __builtin_amdgcn_mfma_f32_16x16x32_f16(qf[kk], b1, c1, 0, 0, 0);
        }

        // ---- online softmax, fully in-register (rows = hi4*4+r) ----
        float corr[4], p0[4], p1[4];
        bool any = false;
        #pragma unroll
        for (int r = 0; r < 4; ++r) {
            float rm = fmaxf(c0[r], c1[r]);
            rm = fmaxf(rm, __shfl_xor(rm, 1));
            rm = fmaxf(rm, __shfl_xor(rm, 2));
            rm = fmaxf(rm, __shfl_xor(rm, 4));
            rm = fmaxf(rm, __shfl_xor(rm, 8));
            if (rm > m_run[r]) { corr[r] = __expf(m_run[r] - rm); m_run[r] = rm; any = true; }
            else corr[r] = 1.f;
            p0[r] = __expf(c0[r] - m_run[r]);
            p1[r] = __expf(c1[r] - m_run[r]);
            float ps = p0[r] + p1[r];
            ps += __shfl_xor(ps, 1);
            ps += __shfl_xor(ps, 2);
            ps += __shfl_xor(ps, 4);
            ps += __shfl_xor(ps, 8);
            l_run[r] = l_run[r] * corr[r] + ps;
        }
        if (any) {   // defer-rescale: skip when no row max moved (T13-style)
            #pragma unroll
            for (int j = 0; j < 16; ++j) {
                #pragma unroll
                for (int r = 0; r < 4; ++r) { accM[j][r] *= corr[r]; accE[j][r] *= corr[r]; }
            }
        }

        // ---- P -> LDS fp16 (wave-local; same wave reads it back) ----
        #pragma unroll
        for (int r = 0; r < 4; ++r) {
            int q = 16 * w + hi4 * 4 + r;
            int ka = lo16, kb = 16 + lo16;
            Pl[q * 32 + (((ka >> 3) ^ (q & 3)) << 3) + (ka & 7)] = (_Float16)p0[r];
            Pl[q * 32 + (((kb >> 3) ^ (q & 3)) << 3) + (kb & 7)] = (_Float16)p1[r];
        }

        // ---- PV: 16 n-tiles x {Vh, V2h, V2l} ----
        {
            int q = 16 * w + lo16;
            half8 pa = *(const half8*)&Pl[q * 32 + ((hi4 ^ (q & 3)) << 3)];
            #pragma unroll
            for (int j = 0; j < 16; ++j) {
                int d = j * 16 + lo16;
                int p = d * 32 + ((hi4 ^ ((d >> 1) & 3)) << 3);
                half8 bh  = *(const half8*)&Vh[p];
                accM[j] = __builtin_amdgcn_mfma_f32_16x16x32_f16(pa, bh, accM[j], 0, 0, 0);
                half8 b2h = *(const half8*)&V2h[p];
                half8 b2l = *(const half8*)&V2l[p];
                accE[j] = __builtin_amdgcn_mfma_f32_16x16x32_f16(pa, b2h, accE[j], 0, 0, 0);
                accE[j] = __builtin_amdgcn_mfma_f32_16x16x32_f16(pa, b2l, accE[j], 0, 0, 0);
            }
        }

        __syncthreads();                       // all LDS reads of chunk kc done
        if (kc + 1 < NCHUNK) { commit(); __syncthreads(); }
    }

    // ---- fused epilogue ----
    const float* mfc = stats_fcs;
    const float* rfc = stats_fcs + B * D;
    #pragma unroll
    for (int r = 0; r < 4; ++r) {
        float linv = 1.f / l_run[r];
        int q = q0 + 16 * w + hi4 * 4 + r;
        size_t rowb = ((size_t)(b * T + q)) * D;
        #pragma unroll
        for (int j = 0; j < 16; ++j) {
            int d = j * 16 + lo16;
            float M  = accM[j][r] * linv;
            float E2 = accE[j][r] * linv;
            float S  = sqrtf(fmaxf(E2 - M * M, 1e-6f));
            float f  = fcs[rowb + d];
            out[rowb + d] = S * ((f - mfc[b * D + d]) * rfc[b * D + d]) + M;
        }
    }
}

// ---------------------------------------------------------------------------
extern "C" void kernel_launch(void* const* d_in, const int* in_sizes, int n_in,
                              void* d_out, int out_size, void* d_ws, size_t ws_size,
                              hipStream_t stream)
{
    const float* fc  = (const float*)d_in[0];
    const float* fs  = (const float*)d_in[1];
    const float* fcs = (const float*)d_in[2];
    const float* Wf  = (const float*)d_in[3];
    const float* bf  = (const float*)d_in[4];
    const float* Wg  = (const float*)d_in[5];
    const float* bg  = (const float*)d_in[6];
    const float* Wh  = (const float*)d_in[7];
    const float* bh  = (const float*)d_in[8];
    float* out = (float*)d_out;

    char* ws = (char*)d_ws;
    float* stats = (float*)ws;                           // 6144 floats
    float* part  = (float*)(ws + (64 << 10));            // 98304 floats
    _Float16* Qg  = (_Float16*)(ws + (1 << 20));         // 8 MB each
    _Float16* Kg  = Qg + (size_t)B * T * D;
    _Float16* Vtg = Kg + (size_t)B * T * D;

    k_stats_part<<<3 * B * NCH, 256, 0, stream>>>(fc, fs, fcs, part);
    k_stats_final<<<3 * B, 256, 0, stream>>>(part, stats);

    float* st_fc  = stats + 0 * 2 * B * D;
    float* st_fs  = stats + 1 * 2 * B * D;
    float* st_fcs = stats + 2 * 2 * B * D;

    k_gemm<<<(B * T) / 64, 256, 0, stream>>>(fc, Wf, bf, st_fc, Qg,  1, 1);
    k_gemm<<<(B * T) / 64, 256, 0, stream>>>(fs, Wg, bg, st_fs, Kg,  1, 1);
    k_gemm<<<(B * T) / 64, 256, 0, stream>>>(fs, Wh, bh, st_fs, Vtg, 0, 2);

    k_attn<<<B * (T / 64), 256, 0, stream>>>(Qg, Kg, Vtg, fcs, st_fcs, out);
}

// Round 4
// 389.506 us; speedup vs baseline: 11.3111x; 1.9952x over previous
//
#include <hip/hip_runtime.h>
#include <math.h>

#define B 4
#define T 4096
#define D 256
#define NCH 16
#define CHT (T / NCH)
#define KC 32
#define NCHUNK (T / KC)

typedef __attribute__((ext_vector_type(8))) _Float16 half8;
typedef __attribute__((ext_vector_type(4))) _Float16 half4;
typedef __attribute__((ext_vector_type(4))) float f32x4;

// ---------------------------------------------------------------------------
// Stage 1a: partial sums for instance-norm stats.
// ---------------------------------------------------------------------------
__global__ __launch_bounds__(256) void k_stats_part(
    const float* __restrict__ fc, const float* __restrict__ fs,
    const float* __restrict__ fcs, float* __restrict__ part)
{
    int blk = blockIdx.x;                 // 3*B*NCH
    int tensor = blk / (B * NCH);
    int rem = blk % (B * NCH);
    int b = rem / NCH, ch = rem % NCH;
    const float* x = (tensor == 0) ? fc : ((tensor == 1) ? fs : fcs);
    int c = threadIdx.x;
    const float* p = x + ((size_t)b * T + (size_t)ch * CHT) * D + c;
    float s = 0.f, ss = 0.f;
    for (int t = 0; t < CHT; ++t) {
        float v = p[(size_t)t * D];
        s += v; ss += v * v;
    }
    float* o = part + (((size_t)tensor * B + b) * NCH + ch) * 2 * D;
    o[c] = s;
    o[D + c] = ss;
}

// ---------------------------------------------------------------------------
// Stage 1b: finalize mean / rstd.
// ---------------------------------------------------------------------------
__global__ __launch_bounds__(256) void k_stats_final(
    const float* __restrict__ part, float* __restrict__ stats)
{
    int blk = blockIdx.x;                 // 3*B
    int tensor = blk / B, b = blk % B;
    int c = threadIdx.x;
    const float* pp = part + (((size_t)tensor * B + b) * NCH) * 2 * D;
    float s = 0.f, ss = 0.f;
    for (int ch = 0; ch < NCH; ++ch) {
        s  += pp[(size_t)ch * 2 * D + c];
        ss += pp[(size_t)ch * 2 * D + D + c];
    }
    float mean = s / (float)T;
    float var  = ss / (float)T - mean * mean;
    float rstd = rsqrtf(var + 1e-5f);
    float* st = stats + (size_t)tensor * 2 * B * D;
    st[(size_t)b * D + c]          = mean;
    st[(size_t)B * D + b * D + c]  = rstd;
}

// ---------------------------------------------------------------------------
// W -> fp16 hi + lo split (exact to ~2^-22 relative).
// ---------------------------------------------------------------------------
__global__ __launch_bounds__(256) void k_wprep(
    const float* __restrict__ Wf, const float* __restrict__ Wg,
    const float* __restrict__ Wh, _Float16* __restrict__ Whi,
    _Float16* __restrict__ Wlo)
{
    int blk = blockIdx.x;                 // 3*256
    int which = blk >> 8, row = blk & 255;
    const float* Wsrc = (which == 0) ? Wf : ((which == 1) ? Wg : Wh);
    int c = threadIdx.x;
    float v = Wsrc[row * 256 + c];
    _Float16 h = (_Float16)v;
    float l = v - (float)h;
    size_t off = ((size_t)which << 16) + (row << 8) + c;
    Whi[off] = h;
    Wlo[off] = (_Float16)l;
}

// ---------------------------------------------------------------------------
// Stage 2: MFMA projection. C[t][o] = (Whi+Wlo)[o][:]·X̂n[t][:] + bias.
// A = X̂ (fp16, LDS, XOR-swizzled), B = W hi/lo from global (L1/L2-resident).
// mode 1: fp16 [t][D] (Q,K).  mode 2: V transposed [b][D][T] + exact v̂² split
// streams V2h/V2l (so attn's commit is pure ds_writes).
// ---------------------------------------------------------------------------
__global__ __launch_bounds__(256) void k_gemm_mfma(
    const float* __restrict__ x, const _Float16* __restrict__ Whi,
    const _Float16* __restrict__ Wlo, const float* __restrict__ bias,
    const float* __restrict__ stats, int use_norm, int mode,
    _Float16* __restrict__ out1,
    _Float16* __restrict__ oV, _Float16* __restrict__ oV2h,
    _Float16* __restrict__ oV2l)
{
    __shared__ _Float16 Xl[64 * 256];
    int m0 = blockIdx.x * 64;
    int b = m0 / T;
    int tid = threadIdx.x;
    const float* mean = stats;
    const float* rstd = stats + B * D;

    // stage + normalize + fp16-convert, XOR-swizzled ((m&7)<<3 halves)
    #pragma unroll
    for (int j = 0; j < 16; ++j) {
        int idx = tid + j * 256;
        int m = idx >> 6, c4 = idx & 63;
        float4 v = *(const float4*)(x + ((size_t)(m0 + m)) * D + c4 * 4);
        if (use_norm) {
            int c = c4 * 4;
            v.x = (v.x - mean[b * D + c + 0]) * rstd[b * D + c + 0];
            v.y = (v.y - mean[b * D + c + 1]) * rstd[b * D + c + 1];
            v.z = (v.z - mean[b * D + c + 2]) * rstd[b * D + c + 2];
            v.w = (v.w - mean[b * D + c + 3]) * rstd[b * D + c + 3];
        }
        half4 h;
        h[0] = (_Float16)v.x; h[1] = (_Float16)v.y;
        h[2] = (_Float16)v.z; h[3] = (_Float16)v.w;
        *(half4*)&Xl[m * 256 + ((c4 * 4) ^ ((m & 7) << 3))] = h;
    }
    __syncthreads();

    const int l = tid & 63, w = tid >> 6;
    const int lo16 = l & 15, hi4 = l >> 4;
    const int row = w * 16 + lo16;

    float bias_v[16];
    #pragma unroll
    for (int nt = 0; nt < 16; ++nt) bias_v[nt] = bias[nt * 16 + lo16];

    f32x4 acc[16];
    #pragma unroll
    for (int nt = 0; nt < 16; ++nt) acc[nt] = (f32x4){0.f, 0.f, 0.f, 0.f};

    #pragma unroll
    for (int kk = 0; kk < 8; ++kk) {
        half8 a = *(const half8*)&Xl[row * 256 + ((kk * 32 + hi4 * 8) ^ ((row & 7) << 3))];
        #pragma unroll
        for (int nt = 0; nt < 16; ++nt) {
            size_t wo = (size_t)(nt * 16 + lo16) * 256 + kk * 32 + hi4 * 8;
            half8 bh = *(const half8*)(Whi + wo);
            acc[nt] = __builtin_amdgcn_mfma_f32_16x16x32_f16(a, bh, acc[nt], 0, 0, 0);
            half8 bl = *(const half8*)(Wlo + wo);
            acc[nt] = __builtin_amdgcn_mfma_f32_16x16x32_f16(a, bl, acc[nt], 0, 0, 0);
        }
    }

    if (mode == 1) {
        #pragma unroll
        for (int nt = 0; nt < 16; ++nt)
            #pragma unroll
            for (int r = 0; r < 4; ++r) {
                int t = m0 + w * 16 + hi4 * 4 + r;
                out1[(size_t)t * D + nt * 16 + lo16] = (_Float16)(acc[nt][r] + bias_v[nt]);
            }
    } else {
        int t0 = (m0 % T) + w * 16 + hi4 * 4;
        #pragma unroll
        for (int nt = 0; nt < 16; ++nt) {
            int o = nt * 16 + lo16;
            half4 vh, h4, l4;
            #pragma unroll
            for (int r = 0; r < 4; ++r) {
                float v = acc[nt][r] + bias_v[nt];
                _Float16 vhh = (_Float16)v;
                float f2 = (float)vhh * (float)vhh;    // exact in fp32
                _Float16 hh = (_Float16)f2;
                float fl = f2 - (float)hh;             // exact residual
                vh[r] = vhh; h4[r] = hh; l4[r] = (_Float16)fl;
            }
            size_t base = ((size_t)b * D + o) * T + t0;
            *(half4*)(oV   + base) = vh;
            *(half4*)(oV2h + base) = h4;
            *(half4*)(oV2l + base) = l4;
        }
    }
}

// ---------------------------------------------------------------------------
// Stage 3: fp16 MFMA flash attention. Double-buffered LDS (1 barrier/chunk),
// deferred softmax (frozen m, per-lane l, rare wave-uniform rescale),
// V/V2h/V2l precomputed. Fused epilogue.
// ---------------------------------------------------------------------------
__global__ __launch_bounds__(256, 1) void k_attn(
    const _Float16* __restrict__ Qg, const _Float16* __restrict__ Kg,
    const _Float16* __restrict__ Vtg, const _Float16* __restrict__ V2hg,
    const _Float16* __restrict__ V2lg, const float* __restrict__ fcs,
    const float* __restrict__ stats_fcs, float* __restrict__ out)
{
    __shared__ __align__(16) _Float16 Kl [2][32 * 256];  // [key][d] swizzled
    __shared__ __align__(16) _Float16 Vl [2][256 * 32];  // [d][key] swizzled
    __shared__ __align__(16) _Float16 V2h[2][256 * 32];
    __shared__ __align__(16) _Float16 V2l[2][256 * 32];
    __shared__ __align__(16) _Float16 Pl[64 * 32];

    const int tid = threadIdx.x;
    const int l = tid & 63;
    const int w = tid >> 6;
    const int b  = blockIdx.x >> 6;
    const int q0 = (blockIdx.x & 63) << 6;
    const int lo16 = l & 15, hi4 = l >> 4;

    short8_check_guard: ;
    half8 qf[8];
    {
        const _Float16* qp = Qg + ((size_t)(b * T + q0 + 16 * w + lo16)) * D + hi4 * 8;
        #pragma unroll
        for (int kk = 0; kk < 8; ++kk) qf[kk] = *(const half8*)(qp + kk * 32);
    }

    f32x4 accM[16], accE[16];
    #pragma unroll
    for (int j = 0; j < 16; ++j) {
        accM[j] = (f32x4){0.f, 0.f, 0.f, 0.f};
        accE[j] = (f32x4){0.f, 0.f, 0.f, 0.f};
    }
    float m_run[4] = {-1e9f, -1e9f, -1e9f, -1e9f};
    float lv[4] = {0.f, 0.f, 0.f, 0.f};          // per-lane partial l

    const _Float16* KgB  = Kg   + (size_t)b * T * D;
    const _Float16* VtB  = Vtg  + (size_t)b * D * T;
    const _Float16* V2hB = V2hg + (size_t)b * D * T;
    const _Float16* V2lB = V2lg + (size_t)b * D * T;

    half8 kreg[4], vreg[4], v2hreg[4], v2lreg[4];

    auto issue = [&](int kc) {
        int k0 = kc * KC;
        #pragma unroll
        for (int i = 0; i < 4; ++i) {
            int g = tid + i * 256;
            kreg[i] = *(const half8*)(KgB + (size_t)(k0 + (g >> 5)) * D + (g & 31) * 8);
        }
        #pragma unroll
        for (int i = 0; i < 4; ++i) {
            int g = tid + i * 256; int d = g >> 2, kg = g & 3;
            size_t off = (size_t)d * T + k0 + kg * 8;
            vreg[i]   = *(const half8*)(VtB  + off);
            v2hreg[i] = *(const half8*)(V2hB + off);
            v2lreg[i] = *(const half8*)(V2lB + off);
        }
    };
    auto commit = [&](int cb) {
        #pragma unroll
        for (int i = 0; i < 4; ++i) {
            int g = tid + i * 256; int rr = g >> 5, cg = g & 31;
            *(half8*)&Kl[cb][rr * 256 + ((cg ^ (rr & 7)) << 3)] = kreg[i];
        }
        #pragma unroll
        for (int i = 0; i < 4; ++i) {
            int g = tid + i * 256; int d = g >> 2, kg = g & 3;
            int p = d * 32 + ((kg ^ ((d >> 1) & 3)) << 3);
            *(half8*)&Vl[cb][p]  = vreg[i];
            *(half8*)&V2h[cb][p] = v2hreg[i];
            *(half8*)&V2l[cb][p] = v2lreg[i];
        }
    };

    issue(0); commit(0); __syncthreads();
    int cur = 0;

    for (int kc = 0; kc < NCHUNK; ++kc) {
        if (kc + 1 < NCHUNK) issue(kc + 1);

        // ---- QK^T ----
        f32x4 c0 = (f32x4){0.f, 0.f, 0.f, 0.f}, c1 = (f32x4){0.f, 0.f, 0.f, 0.f};
        #pragma unroll
        for (int kk = 0; kk < 8; ++kk) {
            int cg = kk * 4 + hi4;
            half8 b0 = *(const half8*)&Kl[cur][lo16 * 256 + ((cg ^ (lo16 & 7)) << 3)];
            half8 b1 = *(const half8*)&Kl[cur][(16 + lo16) * 256 + ((cg ^ ((16 + lo16) & 7)) << 3)];
            c0 = __builtin_amdgcn_mfma_f32_16x16x32_f16(qf[kk], b0, c0, 0, 0, 0);
            c1 = __builtin_amdgcn_mfma_f32_16x16x32_f16(qf[kk], b1, c1, 0, 0, 0);
        }

        // ---- deferred online softmax ----
        float cm[4];
        #pragma unroll
        for (int r = 0; r < 4; ++r) cm[r] = fmaxf(c0[r], c1[r]);
        float tmax = fmaxf(fmaxf(cm[0] - m_run[0], cm[1] - m_run[1]),
                           fmaxf(cm[2] - m_run[2], cm[3] - m_run[3]));
        if (__any(tmax > 10.f)) {              // wave-uniform, rare after warm-up
            float corr[4];
            #pragma unroll
            for (int r = 0; r < 4; ++r) {
                float rm = cm[r];
                rm = fmaxf(rm, __shfl_xor(rm, 1));
                rm = fmaxf(rm, __shfl_xor(rm, 2));
                rm = fmaxf(rm, __shfl_xor(rm, 4));
                rm = fmaxf(rm, __shfl_xor(rm, 8));
                float mn = fmaxf(m_run[r], rm);
                corr[r] = __expf(m_run[r] - mn);
                m_run[r] = mn;
                lv[r] *= corr[r];
            }
            #pragma unroll
            for (int j = 0; j < 16; ++j)
                #pragma unroll
                for (int r = 0; r < 4; ++r) { accM[j][r] *= corr[r]; accE[j][r] *= corr[r]; }
        }
        float p0[4], p1[4];
        #pragma unroll
        for (int r = 0; r < 4; ++r) {
            p0[r] = __expf(c0[r] - m_run[r]);   // bounded by e^10 < fp16 max
            p1[r] = __expf(c1[r] - m_run[r]);
            lv[r] += p0[r] + p1[r];
        }

        // ---- P -> LDS fp16 (wave-local) ----
        #pragma unroll
        for (int r = 0; r < 4; ++r) {
            int q = 16 * w + hi4 * 4 + r;
            int ka = lo16, kb = 16 + lo16;
            Pl[q * 32 + (((ka >> 3) ^ (q & 3)) << 3) + (ka & 7)] = (_Float16)p0[r];
            Pl[q * 32 + (((kb >> 3) ^ (q & 3)) << 3) + (kb & 7)] = (_Float16)p1[r];
        }

        // ---- PV ----
        {
            int q = 16 * w + lo16;
            half8 pa = *(const half8*)&Pl[q * 32 + ((hi4 ^ (q & 3)) << 3)];
            #pragma unroll
            for (int j = 0; j < 16; ++j) {
                int d = j * 16 + lo16;
                int p = d * 32 + ((hi4 ^ ((d >> 1) & 3)) << 3);
                half8 bh  = *(const half8*)&Vl[cur][p];
                accM[j] = __builtin_amdgcn_mfma_f32_16x16x32_f16(pa, bh, accM[j], 0, 0, 0);
                half8 b2h = *(const half8*)&V2h[cur][p];
                half8 b2l = *(const half8*)&V2l[cur][p];
                accE[j] = __builtin_amdgcn_mfma_f32_16x16x32_f16(pa, b2h, accE[j], 0, 0, 0);
                accE[j] = __builtin_amdgcn_mfma_f32_16x16x32_f16(pa, b2l, accE[j], 0, 0, 0);
            }
        }

        if (kc + 1 < NCHUNK) {
            commit(cur ^ 1);      // writes other buffer: no pre-barrier needed
            __syncthreads();      // single barrier per chunk
            cur ^= 1;
        }
    }

    // ---- fused epilogue ----
    const float* mfc = stats_fcs;
    const float* rfc = stats_fcs + B * D;
    #pragma unroll
    for (int r = 0; r < 4; ++r) {
        float lr = lv[r];
        lr += __shfl_xor(lr, 1);
        lr += __shfl_xor(lr, 2);
        lr += __shfl_xor(lr, 4);
        lr += __shfl_xor(lr, 8);
        float linv = 1.f / lr;
        int q = q0 + 16 * w + hi4 * 4 + r;
        size_t rowb = ((size_t)(b * T + q)) * D;
        #pragma unroll
        for (int j = 0; j < 16; ++j) {
            int d = j * 16 + lo16;
            float M  = accM[j][r] * linv;
            float E2 = accE[j][r] * linv;
            float S  = sqrtf(fmaxf(E2 - M * M, 1e-6f));
            float f  = fcs[rowb + d];
            out[rowb + d] = S * ((f - mfc[b * D + d]) * rfc[b * D + d]) + M;
        }
    }
}

// ---------------------------------------------------------------------------
extern "C" void kernel_launch(void* const* d_in, const int* in_sizes, int n_in,
                              void* d_out, int out_size, void* d_ws, size_t ws_size,
                              hipStream_t stream)
{
    const float* fc  = (const float*)d_in[0];
    const float* fs  = (const float*)d_in[1];
    const float* fcs = (const float*)d_in[2];
    const float* Wf  = (const float*)d_in[3];
    const float* bf  = (const float*)d_in[4];
    const float* Wg  = (const float*)d_in[5];
    const float* bg  = (const float*)d_in[6];
    const float* Wh  = (const float*)d_in[7];
    const float* bh  = (const float*)d_in[8];
    float* out = (float*)d_out;

    char* ws = (char*)d_ws;
    float* stats = (float*)ws;                           // 24 KB
    float* part  = (float*)(ws + (64 << 10));            // 384 KB
    _Float16* Whi = (_Float16*)(ws + (512 << 10));       // 3*128 KB
    _Float16* Wlo = Whi + 3 * 65536;                     // 3*128 KB
    _Float16* Qg   = (_Float16*)(ws + (2 << 20));        // 8 MB each
    _Float16* Kg   = Qg  + (size_t)B * T * D;
    _Float16* Vtg  = Kg  + (size_t)B * T * D;
    _Float16* V2hg = Vtg + (size_t)B * T * D;
    _Float16* V2lg = V2hg + (size_t)B * T * D;

    k_stats_part<<<3 * B * NCH, 256, 0, stream>>>(fc, fs, fcs, part);
    k_stats_final<<<3 * B, 256, 0, stream>>>(part, stats);
    k_wprep<<<3 * 256, 256, 0, stream>>>(Wf, Wg, Wh, Whi, Wlo);

    float* st_fc  = stats + 0 * 2 * B * D;
    float* st_fs  = stats + 1 * 2 * B * D;
    float* st_fcs = stats + 2 * 2 * B * D;

    k_gemm_mfma<<<(B * T) / 64, 256, 0, stream>>>(fc, Whi,             Wlo,             bf, st_fc, 1, 1, Qg, nullptr, nullptr, nullptr);
    k_gemm_mfma<<<(B * T) / 64, 256, 0, stream>>>(fs, Whi + 65536,     Wlo + 65536,     bg, st_fs, 1, 1, Kg, nullptr, nullptr, nullptr);
    k_gemm_mfma<<<(B * T) / 64, 256, 0, stream>>>(fs, Whi + 2 * 65536, Wlo + 2 * 65536, bh, st_fs, 0, 2, nullptr, Vtg, V2hg, V2lg);

    k_attn<<<B * (T / 64), 256, 0, stream>>>(Qg, Kg, Vtg, V2hg, V2lg, fcs, st_fcs, out);
}

// Round 5
// 369.451 us; speedup vs baseline: 11.9251x; 1.0543x over previous
//
#include <hip/hip_runtime.h>
#include <math.h>

#define B 4
#define T 4096
#define D 256
#define NCH 16
#define CHT (T / NCH)
#define KC 32
#define NCHUNK (T / KC)

typedef __attribute__((ext_vector_type(8))) _Float16 half8;
typedef __attribute__((ext_vector_type(4))) _Float16 half4;
typedef __attribute__((ext_vector_type(4))) float f32x4;

// ---------------------------------------------------------------------------
// Stage 1a: partial sums for instance-norm stats.
// ---------------------------------------------------------------------------
__global__ __launch_bounds__(256) void k_stats_part(
    const float* __restrict__ fc, const float* __restrict__ fs,
    const float* __restrict__ fcs, float* __restrict__ part)
{
    int blk = blockIdx.x;                 // 3*B*NCH
    int tensor = blk / (B * NCH);
    int rem = blk % (B * NCH);
    int b = rem / NCH, ch = rem % NCH;
    const float* x = (tensor == 0) ? fc : ((tensor == 1) ? fs : fcs);
    int c = threadIdx.x;
    const float* p = x + ((size_t)b * T + (size_t)ch * CHT) * D + c;
    float s = 0.f, ss = 0.f;
    for (int t = 0; t < CHT; ++t) {
        float v = p[(size_t)t * D];
        s += v; ss += v * v;
    }
    float* o = part + (((size_t)tensor * B + b) * NCH + ch) * 2 * D;
    o[c] = s;
    o[D + c] = ss;
}

// ---------------------------------------------------------------------------
// Stage 1b: finalize mean / rstd.
// ---------------------------------------------------------------------------
__global__ __launch_bounds__(256) void k_stats_final(
    const float* __restrict__ part, float* __restrict__ stats)
{
    int blk = blockIdx.x;                 // 3*B
    int tensor = blk / B, b = blk % B;
    int c = threadIdx.x;
    const float* pp = part + (((size_t)tensor * B + b) * NCH) * 2 * D;
    float s = 0.f, ss = 0.f;
    for (int ch = 0; ch < NCH; ++ch) {
        s  += pp[(size_t)ch * 2 * D + c];
        ss += pp[(size_t)ch * 2 * D + D + c];
    }
    float mean = s / (float)T;
    float var  = ss / (float)T - mean * mean;
    float rstd = rsqrtf(var + 1e-5f);
    float* st = stats + (size_t)tensor * 2 * B * D;
    st[(size_t)b * D + c]          = mean;
    st[(size_t)B * D + b * D + c]  = rstd;
}

// ---------------------------------------------------------------------------
// W -> fp16 hi + lo split (exact to ~2^-22 relative).
// ---------------------------------------------------------------------------
__global__ __launch_bounds__(256) void k_wprep(
    const float* __restrict__ Wf, const float* __restrict__ Wg,
    const float* __restrict__ Wh, _Float16* __restrict__ Whi,
    _Float16* __restrict__ Wlo)
{
    int blk = blockIdx.x;                 // 3*256
    int which = blk >> 8, row = blk & 255;
    const float* Wsrc = (which == 0) ? Wf : ((which == 1) ? Wg : Wh);
    int c = threadIdx.x;
    float v = Wsrc[row * 256 + c];
    _Float16 h = (_Float16)v;
    float l = v - (float)h;
    size_t off = ((size_t)which << 16) + (row << 8) + c;
    Whi[off] = h;
    Wlo[off] = (_Float16)l;
}

// ---------------------------------------------------------------------------
// Stage 2: MFMA projection. C[t][o] = (Whi+Wlo)[o][:]·X̂n[t][:] + bias.
// mode 1: fp16 [t][D] (Q,K).  mode 2: V transposed [b][D][T] + exact v̂² split
// streams V2h/V2l.
// ---------------------------------------------------------------------------
__global__ __launch_bounds__(256) void k_gemm_mfma(
    const float* __restrict__ x, const _Float16* __restrict__ Whi,
    const _Float16* __restrict__ Wlo, const float* __restrict__ bias,
    const float* __restrict__ stats, int use_norm, int mode,
    _Float16* __restrict__ out1,
    _Float16* __restrict__ oV, _Float16* __restrict__ oV2h,
    _Float16* __restrict__ oV2l)
{
    __shared__ _Float16 Xl[64 * 256];
    int m0 = blockIdx.x * 64;
    int b = m0 / T;
    int tid = threadIdx.x;
    const float* mean = stats;
    const float* rstd = stats + B * D;

    #pragma unroll
    for (int j = 0; j < 16; ++j) {
        int idx = tid + j * 256;
        int m = idx >> 6, c4 = idx & 63;
        float4 v = *(const float4*)(x + ((size_t)(m0 + m)) * D + c4 * 4);
        if (use_norm) {
            int c = c4 * 4;
            v.x = (v.x - mean[b * D + c + 0]) * rstd[b * D + c + 0];
            v.y = (v.y - mean[b * D + c + 1]) * rstd[b * D + c + 1];
            v.z = (v.z - mean[b * D + c + 2]) * rstd[b * D + c + 2];
            v.w = (v.w - mean[b * D + c + 3]) * rstd[b * D + c + 3];
        }
        half4 h;
        h[0] = (_Float16)v.x; h[1] = (_Float16)v.y;
        h[2] = (_Float16)v.z; h[3] = (_Float16)v.w;
        *(half4*)&Xl[m * 256 + ((c4 * 4) ^ ((m & 7) << 3))] = h;
    }
    __syncthreads();

    const int l = tid & 63, w = tid >> 6;
    const int lo16 = l & 15, hi4 = l >> 4;
    const int row = w * 16 + lo16;

    float bias_v[16];
    #pragma unroll
    for (int nt = 0; nt < 16; ++nt) bias_v[nt] = bias[nt * 16 + lo16];

    f32x4 acc[16];
    #pragma unroll
    for (int nt = 0; nt < 16; ++nt) acc[nt] = (f32x4){0.f, 0.f, 0.f, 0.f};

    #pragma unroll
    for (int kk = 0; kk < 8; ++kk) {
        half8 a = *(const half8*)&Xl[row * 256 + ((kk * 32 + hi4 * 8) ^ ((row & 7) << 3))];
        #pragma unroll
        for (int nt = 0; nt < 16; ++nt) {
            size_t wo = (size_t)(nt * 16 + lo16) * 256 + kk * 32 + hi4 * 8;
            half8 bh = *(const half8*)(Whi + wo);
            acc[nt] = __builtin_amdgcn_mfma_f32_16x16x32_f16(a, bh, acc[nt], 0, 0, 0);
            half8 bl = *(const half8*)(Wlo + wo);
            acc[nt] = __builtin_amdgcn_mfma_f32_16x16x32_f16(a, bl, acc[nt], 0, 0, 0);
        }
    }

    if (mode == 1) {
        #pragma unroll
        for (int nt = 0; nt < 16; ++nt)
            #pragma unroll
            for (int r = 0; r < 4; ++r) {
                int t = m0 + w * 16 + hi4 * 4 + r;
                out1[(size_t)t * D + nt * 16 + lo16] = (_Float16)(acc[nt][r] + bias_v[nt]);
            }
    } else {
        int t0 = (m0 % T) + w * 16 + hi4 * 4;
        #pragma unroll
        for (int nt = 0; nt < 16; ++nt) {
            int o = nt * 16 + lo16;
            half4 vh, h4, l4;
            #pragma unroll
            for (int r = 0; r < 4; ++r) {
                float v = acc[nt][r] + bias_v[nt];
                _Float16 vhh = (_Float16)v;
                float f2 = (float)vhh * (float)vhh;    // exact in fp32
                _Float16 hh = (_Float16)f2;
                float fl = f2 - (float)hh;             // exact residual
                vh[r] = vhh; h4[r] = hh; l4[r] = (_Float16)fl;
            }
            size_t base = ((size_t)b * D + o) * T + t0;
            *(half4*)(oV   + base) = vh;
            *(half4*)(oV2h + base) = h4;
            *(half4*)(oV2l + base) = l4;
        }
    }
}

// ---------------------------------------------------------------------------
// Stage 3: fp16 MFMA flash attention. 8 waves / 512 threads:
// wave pairs (w, w+4) own the same 16 q-rows; both compute QK^T+softmax
// (bit-identical, duplicate Pl writes benign), PV split by d-half
// (8 j-tiles/wave). Double-buffered K/V LDS, 1 barrier/chunk, deferred
// softmax, fused epilogue. 2 waves/SIMD.
// ---------------------------------------------------------------------------
__global__ __launch_bounds__(512, 2) void k_attn(
    const _Float16* __restrict__ Qg, const _Float16* __restrict__ Kg,
    const _Float16* __restrict__ Vtg, const _Float16* __restrict__ V2hg,
    const _Float16* __restrict__ V2lg, const float* __restrict__ fcs,
    const float* __restrict__ stats_fcs, float* __restrict__ out)
{
    __shared__ __align__(16) _Float16 Kl [2][32 * 256];  // [key][d] swizzled
    __shared__ __align__(16) _Float16 Vl [2][256 * 32];  // [d][key] swizzled
    __shared__ __align__(16) _Float16 V2h[2][256 * 32];
    __shared__ __align__(16) _Float16 V2l[2][256 * 32];
    __shared__ __align__(16) _Float16 Pl[64 * 32];

    const int tid = threadIdx.x;
    const int l = tid & 63;
    const int w = tid >> 6;               // 0..7
    const int wq = w & 3;                 // q-subtile (16 rows)
    const int jbase = (w >> 2) * 8;       // d-half: j tiles jbase..jbase+7
    const int b  = blockIdx.x >> 6;
    const int q0 = (blockIdx.x & 63) << 6;
    const int lo16 = l & 15, hi4 = l >> 4;

    half8 qf[8];
    {
        const _Float16* qp = Qg + ((size_t)(b * T + q0 + 16 * wq + lo16)) * D + hi4 * 8;
        #pragma unroll
        for (int kk = 0; kk < 8; ++kk) qf[kk] = *(const half8*)(qp + kk * 32);
    }

    f32x4 accM[8], accE[8];
    #pragma unroll
    for (int j = 0; j < 8; ++j) {
        accM[j] = (f32x4){0.f, 0.f, 0.f, 0.f};
        accE[j] = (f32x4){0.f, 0.f, 0.f, 0.f};
    }
    float m_run[4] = {-1e9f, -1e9f, -1e9f, -1e9f};
    float lv[4] = {0.f, 0.f, 0.f, 0.f};          // per-lane partial l

    const _Float16* KgB  = Kg   + (size_t)b * T * D;
    const _Float16* VtB  = Vtg  + (size_t)b * D * T;
    const _Float16* V2hB = V2hg + (size_t)b * D * T;
    const _Float16* V2lB = V2lg + (size_t)b * D * T;

    half8 kreg[2], vreg[2], v2hreg[2], v2lreg[2];

    auto issue = [&](int kc) {
        int k0 = kc * KC;
        #pragma unroll
        for (int i = 0; i < 2; ++i) {
            int g = tid + i * 512;                    // 0..1023: row=g>>5, cg=g&31
            kreg[i] = *(const half8*)(KgB + (size_t)(k0 + (g >> 5)) * D + (g & 31) * 8);
        }
        #pragma unroll
        for (int i = 0; i < 2; ++i) {
            int g = tid + i * 512;                    // d=g>>2, kg=g&3
            size_t off = (size_t)(g >> 2) * T + k0 + (g & 3) * 8;
            vreg[i]   = *(const half8*)(VtB  + off);
            v2hreg[i] = *(const half8*)(V2hB + off);
            v2lreg[i] = *(const half8*)(V2lB + off);
        }
    };
    auto commit = [&](int cb) {
        #pragma unroll
        for (int i = 0; i < 2; ++i) {
            int g = tid + i * 512; int rr = g >> 5, cg = g & 31;
            *(half8*)&Kl[cb][rr * 256 + ((cg ^ (rr & 7)) << 3)] = kreg[i];
        }
        #pragma unroll
        for (int i = 0; i < 2; ++i) {
            int g = tid + i * 512; int d = g >> 2, kg = g & 3;
            int p = d * 32 + ((kg ^ ((d >> 1) & 3)) << 3);
            *(half8*)&Vl[cb][p]  = vreg[i];
            *(half8*)&V2h[cb][p] = v2hreg[i];
            *(half8*)&V2l[cb][p] = v2lreg[i];
        }
    };

    issue(0); commit(0); __syncthreads();
    int cur = 0;

    for (int kc = 0; kc < NCHUNK; ++kc) {
        if (kc + 1 < NCHUNK) issue(kc + 1);

        // ---- QK^T (duplicated across the wave pair; bit-identical) ----
        f32x4 c0 = (f32x4){0.f, 0.f, 0.f, 0.f}, c1 = (f32x4){0.f, 0.f, 0.f, 0.f};
        #pragma unroll
        for (int kk = 0; kk < 8; ++kk) {
            int cg = kk * 4 + hi4;
            half8 b0 = *(const half8*)&Kl[cur][lo16 * 256 + ((cg ^ (lo16 & 7)) << 3)];
            half8 b1 = *(const half8*)&Kl[cur][(16 + lo16) * 256 + ((cg ^ ((16 + lo16) & 7)) << 3)];
            c0 = __builtin_amdgcn_mfma_f32_16x16x32_f16(qf[kk], b0, c0, 0, 0, 0);
            c1 = __builtin_amdgcn_mfma_f32_16x16x32_f16(qf[kk], b1, c1, 0, 0, 0);
        }

        // ---- deferred online softmax ----
        float cm[4];
        #pragma unroll
        for (int r = 0; r < 4; ++r) cm[r] = fmaxf(c0[r], c1[r]);
        float tmax = fmaxf(fmaxf(cm[0] - m_run[0], cm[1] - m_run[1]),
                           fmaxf(cm[2] - m_run[2], cm[3] - m_run[3]));
        if (__any(tmax > 10.f)) {              // wave-uniform, rare after warm-up
            float corr[4];
            #pragma unroll
            for (int r = 0; r < 4; ++r) {
                float rm = cm[r];
                rm = fmaxf(rm, __shfl_xor(rm, 1));
                rm = fmaxf(rm, __shfl_xor(rm, 2));
                rm = fmaxf(rm, __shfl_xor(rm, 4));
                rm = fmaxf(rm, __shfl_xor(rm, 8));
                float mn = fmaxf(m_run[r], rm);
                corr[r] = __expf(m_run[r] - mn);
                m_run[r] = mn;
                lv[r] *= corr[r];
            }
            #pragma unroll
            for (int j = 0; j < 8; ++j)
                #pragma unroll
                for (int r = 0; r < 4; ++r) { accM[j][r] *= corr[r]; accE[j][r] *= corr[r]; }
        }
        float p0[4], p1[4];
        #pragma unroll
        for (int r = 0; r < 4; ++r) {
            p0[r] = __expf(c0[r] - m_run[r]);   // bounded by e^10 < fp16 max
            p1[r] = __expf(c1[r] - m_run[r]);
            lv[r] += p0[r] + p1[r];
        }

        // ---- P -> LDS fp16 (wave pairs write identical values) ----
        #pragma unroll
        for (int r = 0; r < 4; ++r) {
            int q = 16 * wq + hi4 * 4 + r;
            int ka = lo16, kb = 16 + lo16;
            Pl[q * 32 + (((ka >> 3) ^ (q & 3)) << 3) + (ka & 7)] = (_Float16)p0[r];
            Pl[q * 32 + (((kb >> 3) ^ (q & 3)) << 3) + (kb & 7)] = (_Float16)p1[r];
        }

        // ---- PV (d-half per wave) ----
        {
            int q = 16 * wq + lo16;
            half8 pa = *(const half8*)&Pl[q * 32 + ((hi4 ^ (q & 3)) << 3)];
            #pragma unroll
            for (int jj = 0; jj < 8; ++jj) {
                int d = (jbase + jj) * 16 + lo16;
                int p = d * 32 + ((hi4 ^ ((d >> 1) & 3)) << 3);
                half8 bh  = *(const half8*)&Vl[cur][p];
                accM[jj] = __builtin_amdgcn_mfma_f32_16x16x32_f16(pa, bh, accM[jj], 0, 0, 0);
                half8 b2h = *(const half8*)&V2h[cur][p];
                half8 b2l = *(const half8*)&V2l[cur][p];
                accE[jj] = __builtin_amdgcn_mfma_f32_16x16x32_f16(pa, b2h, accE[jj], 0, 0, 0);
                accE[jj] = __builtin_amdgcn_mfma_f32_16x16x32_f16(pa, b2l, accE[jj], 0, 0, 0);
            }
        }

        if (kc + 1 < NCHUNK) {
            commit(cur ^ 1);      // other buffer: no pre-barrier needed
            __syncthreads();      // single barrier per chunk
            cur ^= 1;
        }
    }

    // ---- fused epilogue ----
    const float* mfc = stats_fcs;
    const float* rfc = stats_fcs + B * D;
    #pragma unroll
    for (int r = 0; r < 4; ++r) {
        float lr = lv[r];
        lr += __shfl_xor(lr, 1);
        lr += __shfl_xor(lr, 2);
        lr += __shfl_xor(lr, 4);
        lr += __shfl_xor(lr, 8);
        float linv = 1.f / lr;
        int q = q0 + 16 * wq + hi4 * 4 + r;
        size_t rowb = ((size_t)(b * T + q)) * D;
        #pragma unroll
        for (int jj = 0; jj < 8; ++jj) {
            int d = (jbase + jj) * 16 + lo16;
            float M  = accM[jj][r] * linv;
            float E2 = accE[jj][r] * linv;
            float S  = sqrtf(fmaxf(E2 - M * M, 1e-6f));
            float f  = fcs[rowb + d];
            out[rowb + d] = S * ((f - mfc[b * D + d]) * rfc[b * D + d]) + M;
        }
    }
}

// ---------------------------------------------------------------------------
extern "C" void kernel_launch(void* const* d_in, const int* in_sizes, int n_in,
                              void* d_out, int out_size, void* d_ws, size_t ws_size,
                              hipStream_t stream)
{
    const float* fc  = (const float*)d_in[0];
    const float* fs  = (const float*)d_in[1];
    const float* fcs = (const float*)d_in[2];
    const float* Wf  = (const float*)d_in[3];
    const float* bf  = (const float*)d_in[4];
    const float* Wg  = (const float*)d_in[5];
    const float* bg  = (const float*)d_in[6];
    const float* Wh  = (const float*)d_in[7];
    const float* bh  = (const float*)d_in[8];
    float* out = (float*)d_out;

    char* ws = (char*)d_ws;
    float* stats = (float*)ws;                           // 24 KB
    float* part  = (float*)(ws + (64 << 10));            // 384 KB
    _Float16* Whi = (_Float16*)(ws + (512 << 10));       // 3*128 KB
    _Float16* Wlo = Whi + 3 * 65536;                     // 3*128 KB
    _Float16* Qg   = (_Float16*)(ws + (2 << 20));        // 8 MB each
    _Float16* Kg   = Qg  + (size_t)B * T * D;
    _Float16* Vtg  = Kg  + (size_t)B * T * D;
    _Float16* V2hg = Vtg + (size_t)B * T * D;
    _Float16* V2lg = V2hg + (size_t)B * T * D;

    k_stats_part<<<3 * B * NCH, 256, 0, stream>>>(fc, fs, fcs, part);
    k_stats_final<<<3 * B, 256, 0, stream>>>(part, stats);
    k_wprep<<<3 * 256, 256, 0, stream>>>(Wf, Wg, Wh, Whi, Wlo);

    float* st_fc  = stats + 0 * 2 * B * D;
    float* st_fs  = stats + 1 * 2 * B * D;
    float* st_fcs = stats + 2 * 2 * B * D;

    k_gemm_mfma<<<(B * T) / 64, 256, 0, stream>>>(fc, Whi,             Wlo,             bf, st_fc, 1, 1, Qg, nullptr, nullptr, nullptr);
    k_gemm_mfma<<<(B * T) / 64, 256, 0, stream>>>(fs, Whi + 65536,     Wlo + 65536,     bg, st_fs, 1, 1, Kg, nullptr, nullptr, nullptr);
    k_gemm_mfma<<<(B * T) / 64, 256, 0, stream>>>(fs, Whi + 2 * 65536, Wlo + 2 * 65536, bh, st_fs, 0, 2, nullptr, Vtg, V2hg, V2lg);

    k_attn<<<B * (T / 64), 512, 0, stream>>>(Qg, Kg, Vtg, V2hg, V2lg, fcs, st_fcs, out);
}

// Round 6
// 366.161 us; speedup vs baseline: 12.0322x; 1.0090x over previous
//
#include <hip/hip_runtime.h>
#include <math.h>

#define B 4
#define T 4096
#define D 256
#define NCH 16
#define CHT (T / NCH)
#define KC 32
#define NCHUNK (T / KC)

typedef __attribute__((ext_vector_type(8))) _Float16 half8;
typedef __attribute__((ext_vector_type(4))) _Float16 half4;
typedef __attribute__((ext_vector_type(4))) float f32x4;

// ---------------------------------------------------------------------------
// Stage 1a: partial sums for instance-norm stats.
// ---------------------------------------------------------------------------
__global__ __launch_bounds__(256) void k_stats_part(
    const float* __restrict__ fc, const float* __restrict__ fs,
    const float* __restrict__ fcs, float* __restrict__ part)
{
    int blk = blockIdx.x;                 // 3*B*NCH
    int tensor = blk / (B * NCH);
    int rem = blk % (B * NCH);
    int b = rem / NCH, ch = rem % NCH;
    const float* x = (tensor == 0) ? fc : ((tensor == 1) ? fs : fcs);
    int c = threadIdx.x;
    const float* p = x + ((size_t)b * T + (size_t)ch * CHT) * D + c;
    float s = 0.f, ss = 0.f;
    for (int t = 0; t < CHT; ++t) {
        float v = p[(size_t)t * D];
        s += v; ss += v * v;
    }
    float* o = part + (((size_t)tensor * B + b) * NCH + ch) * 2 * D;
    o[c] = s;
    o[D + c] = ss;
}

// ---------------------------------------------------------------------------
// Stage 1b: finalize mean / rstd.
// ---------------------------------------------------------------------------
__global__ __launch_bounds__(256) void k_stats_final(
    const float* __restrict__ part, float* __restrict__ stats)
{
    int blk = blockIdx.x;                 // 3*B
    int tensor = blk / B, b = blk % B;
    int c = threadIdx.x;
    const float* pp = part + (((size_t)tensor * B + b) * NCH) * 2 * D;
    float s = 0.f, ss = 0.f;
    for (int ch = 0; ch < NCH; ++ch) {
        s  += pp[(size_t)ch * 2 * D + c];
        ss += pp[(size_t)ch * 2 * D + D + c];
    }
    float mean = s / (float)T;
    float var  = ss / (float)T - mean * mean;
    float rstd = rsqrtf(var + 1e-5f);
    float* st = stats + (size_t)tensor * 2 * B * D;
    st[(size_t)b * D + c]          = mean;
    st[(size_t)B * D + b * D + c]  = rstd;
}

// ---------------------------------------------------------------------------
// W -> fp16 hi + lo split (exact to ~2^-22 relative).
// ---------------------------------------------------------------------------
__global__ __launch_bounds__(256) void k_wprep(
    const float* __restrict__ Wf, const float* __restrict__ Wg,
    const float* __restrict__ Wh, _Float16* __restrict__ Whi,
    _Float16* __restrict__ Wlo)
{
    int blk = blockIdx.x;                 // 3*256
    int which = blk >> 8, row = blk & 255;
    const float* Wsrc = (which == 0) ? Wf : ((which == 1) ? Wg : Wh);
    int c = threadIdx.x;
    float v = Wsrc[row * 256 + c];
    _Float16 h = (_Float16)v;
    float l = v - (float)h;
    size_t off = ((size_t)which << 16) + (row << 8) + c;
    Whi[off] = h;
    Wlo[off] = (_Float16)l;
}

// ---------------------------------------------------------------------------
// Stage 2: MFMA projection. C[t][o] = (Whi+Wlo)[o][:]·X̂n[t][:] + bias.
// mode 1: fp16 [t][D] (Q,K).  mode 2: V transposed [b][D][T] + exact v̂² split
// streams V2h/V2l.
// ---------------------------------------------------------------------------
__global__ __launch_bounds__(256) void k_gemm_mfma(
    const float* __restrict__ x, const _Float16* __restrict__ Whi,
    const _Float16* __restrict__ Wlo, const float* __restrict__ bias,
    const float* __restrict__ stats, int use_norm, int mode,
    _Float16* __restrict__ out1,
    _Float16* __restrict__ oV, _Float16* __restrict__ oV2h,
    _Float16* __restrict__ oV2l)
{
    __shared__ _Float16 Xl[64 * 256];
    int m0 = blockIdx.x * 64;
    int b = m0 / T;
    int tid = threadIdx.x;
    const float* mean = stats;
    const float* rstd = stats + B * D;

    #pragma unroll
    for (int j = 0; j < 16; ++j) {
        int idx = tid + j * 256;
        int m = idx >> 6, c4 = idx & 63;
        float4 v = *(const float4*)(x + ((size_t)(m0 + m)) * D + c4 * 4);
        if (use_norm) {
            int c = c4 * 4;
            v.x = (v.x - mean[b * D + c + 0]) * rstd[b * D + c + 0];
            v.y = (v.y - mean[b * D + c + 1]) * rstd[b * D + c + 1];
            v.z = (v.z - mean[b * D + c + 2]) * rstd[b * D + c + 2];
            v.w = (v.w - mean[b * D + c + 3]) * rstd[b * D + c + 3];
        }
        half4 h;
        h[0] = (_Float16)v.x; h[1] = (_Float16)v.y;
        h[2] = (_Float16)v.z; h[3] = (_Float16)v.w;
        *(half4*)&Xl[m * 256 + ((c4 * 4) ^ ((m & 7) << 3))] = h;
    }
    __syncthreads();

    const int l = tid & 63, w = tid >> 6;
    const int lo16 = l & 15, hi4 = l >> 4;
    const int row = w * 16 + lo16;

    float bias_v[16];
    #pragma unroll
    for (int nt = 0; nt < 16; ++nt) bias_v[nt] = bias[nt * 16 + lo16];

    f32x4 acc[16];
    #pragma unroll
    for (int nt = 0; nt < 16; ++nt) acc[nt] = (f32x4){0.f, 0.f, 0.f, 0.f};

    #pragma unroll
    for (int kk = 0; kk < 8; ++kk) {
        half8 a = *(const half8*)&Xl[row * 256 + ((kk * 32 + hi4 * 8) ^ ((row & 7) << 3))];
        #pragma unroll
        for (int nt = 0; nt < 16; ++nt) {
            size_t wo = (size_t)(nt * 16 + lo16) * 256 + kk * 32 + hi4 * 8;
            half8 bh = *(const half8*)(Whi + wo);
            acc[nt] = __builtin_amdgcn_mfma_f32_16x16x32_f16(a, bh, acc[nt], 0, 0, 0);
            half8 bl = *(const half8*)(Wlo + wo);
            acc[nt] = __builtin_amdgcn_mfma_f32_16x16x32_f16(a, bl, acc[nt], 0, 0, 0);
        }
    }

    if (mode == 1) {
        #pragma unroll
        for (int nt = 0; nt < 16; ++nt)
            #pragma unroll
            for (int r = 0; r < 4; ++r) {
                int t = m0 + w * 16 + hi4 * 4 + r;
                out1[(size_t)t * D + nt * 16 + lo16] = (_Float16)(acc[nt][r] + bias_v[nt]);
            }
    } else {
        int t0 = (m0 % T) + w * 16 + hi4 * 4;
        #pragma unroll
        for (int nt = 0; nt < 16; ++nt) {
            int o = nt * 16 + lo16;
            half4 vh, h4, l4;
            #pragma unroll
            for (int r = 0; r < 4; ++r) {
                float v = acc[nt][r] + bias_v[nt];
                _Float16 vhh = (_Float16)v;
                float f2 = (float)vhh * (float)vhh;    // exact in fp32
                _Float16 hh = (_Float16)f2;
                float fl = f2 - (float)hh;             // exact residual
                vh[r] = vhh; h4[r] = hh; l4[r] = (_Float16)fl;
            }
            size_t base = ((size_t)b * D + o) * T + t0;
            *(half4*)(oV   + base) = vh;
            *(half4*)(oV2h + base) = h4;
            *(half4*)(oV2l + base) = l4;
        }
    }
}

// ---------------------------------------------------------------------------
// Stage 3: fp16 MFMA flash attention, phase-split wave specialization.
// 8 waves / 512 threads:
//   Phase A: waves 0-3 = QK^T + softmax for their own 16 q-rows (K dup 4),
//            waves 4-7 = stage next chunk (issue+commit, global->LDS).
//   Phase B: all 8 waves PV, d-split 8-way (V dup 1; P A-frags reused in
//            regs across 4 q-subtiles; B-frags reused across q-subtiles).
// Deferred softmax with flag/corr LDS broadcast. 2 barriers/chunk.
// Arithmetic per output identical to round 5.
// ---------------------------------------------------------------------------
__global__ __launch_bounds__(512, 2) void k_attn(
    const _Float16* __restrict__ Qg, const _Float16* __restrict__ Kg,
    const _Float16* __restrict__ Vtg, const _Float16* __restrict__ V2hg,
    const _Float16* __restrict__ V2lg, const float* __restrict__ fcs,
    const float* __restrict__ stats_fcs, float* __restrict__ out)
{
    __shared__ __align__(16) _Float16 Kl [2][32 * 256];  // [key][d] swizzled
    __shared__ __align__(16) _Float16 Vl [2][256 * 32];  // [d][key] swizzled
    __shared__ __align__(16) _Float16 V2h[2][256 * 32];
    __shared__ __align__(16) _Float16 V2l[2][256 * 32];
    __shared__ __align__(16) _Float16 Pl[64 * 32];
    __shared__ float corr_lds[64];
    __shared__ float l_lds[64];
    __shared__ int   flags[4];

    const int tid = threadIdx.x;
    const int l = tid & 63;
    const int w = tid >> 6;               // 0..7
    const int b  = blockIdx.x >> 6;
    const int q0 = (blockIdx.x & 63) << 6;
    const int lo16 = l & 15, hi4 = l >> 4;

    const _Float16* KgB  = Kg   + (size_t)b * T * D;
    const _Float16* VtB  = Vtg  + (size_t)b * D * T;
    const _Float16* V2hB = V2hg + (size_t)b * D * T;
    const _Float16* V2lB = V2lg + (size_t)b * D * T;

    // Q fragments: only QK waves (w<4), rows q0+16w..+16
    half8 qf[8];
    if (w < 4) {
        const _Float16* qp = Qg + ((size_t)(b * T + q0 + 16 * w + lo16)) * D + hi4 * 8;
        #pragma unroll
        for (int kk = 0; kk < 8; ++kk) qf[kk] = *(const half8*)(qp + kk * 32);
    }

    // PV accumulators: [q-subtile][jj] ; wave w owns d-tiles 2w, 2w+1
    f32x4 accM[4][2], accE[4][2];
    #pragma unroll
    for (int qs = 0; qs < 4; ++qs)
        #pragma unroll
        for (int jj = 0; jj < 2; ++jj) {
            accM[qs][jj] = (f32x4){0.f, 0.f, 0.f, 0.f};
            accE[qs][jj] = (f32x4){0.f, 0.f, 0.f, 0.f};
        }
    float m_run[4] = {-1e9f, -1e9f, -1e9f, -1e9f};
    float lv[4] = {0.f, 0.f, 0.f, 0.f};          // per-lane partial l (QK waves)

    // staging by waves 4-7: full chunk (K + 3 V-streams), 4 iters/thread
    auto stage = [&](int kcs, int cb) {
        int k0 = kcs * KC;
        int t2 = tid & 255;
        half8 kr[4], vr[4], vhr[4], vlr[4];
        #pragma unroll
        for (int i = 0; i < 4; ++i) {
            int g = t2 + i * 256;                 // row=g>>5, cg=g&31
            kr[i] = *(const half8*)(KgB + (size_t)(k0 + (g >> 5)) * D + (g & 31) * 8);
        }
        #pragma unroll
        for (int i = 0; i < 4; ++i) {
            int g = t2 + i * 256; int d = g >> 2, kg = g & 3;
            size_t off = (size_t)d * T + k0 + kg * 8;
            vr[i]  = *(const half8*)(VtB  + off);
            vhr[i] = *(const half8*)(V2hB + off);
            vlr[i] = *(const half8*)(V2lB + off);
        }
        #pragma unroll
        for (int i = 0; i < 4; ++i) {
            int g = t2 + i * 256; int rr = g >> 5, cg = g & 31;
            *(half8*)&Kl[cb][rr * 256 + ((cg ^ (rr & 7)) << 3)] = kr[i];
        }
        #pragma unroll
        for (int i = 0; i < 4; ++i) {
            int g = t2 + i * 256; int d = g >> 2, kg = g & 3;
            int p = d * 32 + ((kg ^ ((d >> 1) & 3)) << 3);
            *(half8*)&Vl[cb][p]  = vr[i];
            *(half8*)&V2h[cb][p] = vhr[i];
            *(half8*)&V2l[cb][p] = vlr[i];
        }
    };

    if (w >= 4) stage(0, 0);
    __syncthreads();
    int cur = 0;

    for (int kc = 0; kc < NCHUNK; ++kc) {
        // ================= Phase A =================
        if (w < 4) {
            // ---- QK^T for this wave's 16 q-rows ----
            f32x4 c0 = (f32x4){0.f, 0.f, 0.f, 0.f}, c1 = (f32x4){0.f, 0.f, 0.f, 0.f};
            #pragma unroll
            for (int kk = 0; kk < 8; ++kk) {
                int cg = kk * 4 + hi4;
                half8 b0 = *(const half8*)&Kl[cur][lo16 * 256 + ((cg ^ (lo16 & 7)) << 3)];
                half8 b1 = *(const half8*)&Kl[cur][(16 + lo16) * 256 + ((cg ^ ((16 + lo16) & 7)) << 3)];
                c0 = __builtin_amdgcn_mfma_f32_16x16x32_f16(qf[kk], b0, c0, 0, 0, 0);
                c1 = __builtin_amdgcn_mfma_f32_16x16x32_f16(qf[kk], b1, c1, 0, 0, 0);
            }

            // ---- deferred online softmax ----
            float cm[4];
            #pragma unroll
            for (int r = 0; r < 4; ++r) cm[r] = fmaxf(c0[r], c1[r]);
            float tmax = fmaxf(fmaxf(cm[0] - m_run[0], cm[1] - m_run[1]),
                               fmaxf(cm[2] - m_run[2], cm[3] - m_run[3]));
            int flagv = 0;
            if (__any(tmax > 10.f)) {
                flagv = 1;
                float corr[4];
                #pragma unroll
                for (int r = 0; r < 4; ++r) {
                    float rm = cm[r];
                    rm = fmaxf(rm, __shfl_xor(rm, 1));
                    rm = fmaxf(rm, __shfl_xor(rm, 2));
                    rm = fmaxf(rm, __shfl_xor(rm, 4));
                    rm = fmaxf(rm, __shfl_xor(rm, 8));
                    float mn = fmaxf(m_run[r], rm);
                    corr[r] = __expf(m_run[r] - mn);
                    m_run[r] = mn;
                    lv[r] *= corr[r];
                }
                if (lo16 == 0) {
                    #pragma unroll
                    for (int r = 0; r < 4; ++r)
                        corr_lds[w * 16 + hi4 * 4 + r] = corr[r];
                }
            }
            if (l == 0) flags[w] = flagv;

            float p0[4], p1[4];
            #pragma unroll
            for (int r = 0; r < 4; ++r) {
                p0[r] = __expf(c0[r] - m_run[r]);   // bounded by e^10 < fp16 max
                p1[r] = __expf(c1[r] - m_run[r]);
                lv[r] += p0[r] + p1[r];
            }
            // ---- P -> LDS fp16 ----
            #pragma unroll
            for (int r = 0; r < 4; ++r) {
                int q = 16 * w + hi4 * 4 + r;
                int ka = lo16, kb = 16 + lo16;
                Pl[q * 32 + (((ka >> 3) ^ (q & 3)) << 3) + (ka & 7)] = (_Float16)p0[r];
                Pl[q * 32 + (((kb >> 3) ^ (q & 3)) << 3) + (kb & 7)] = (_Float16)p1[r];
            }
        } else {
            if (kc + 1 < NCHUNK) stage(kc + 1, cur ^ 1);
        }
        __syncthreads();                  // P, flags, next-chunk LDS ready

        // ================= Phase B (all waves) =================
        // rare deferred rescale, broadcast via flags/corr_lds
        #pragma unroll
        for (int qs = 0; qs < 4; ++qs) {
            if (flags[qs]) {
                #pragma unroll
                for (int r = 0; r < 4; ++r) {
                    float c = corr_lds[qs * 16 + hi4 * 4 + r];
                    accM[qs][0][r] *= c; accM[qs][1][r] *= c;
                    accE[qs][0][r] *= c; accE[qs][1][r] *= c;
                }
            }
        }

        // P A-frags (4 q-subtiles, held in regs)
        half8 pa[4];
        #pragma unroll
        for (int qs = 0; qs < 4; ++qs) {
            int q = qs * 16 + lo16;
            pa[qs] = *(const half8*)&Pl[q * 32 + ((hi4 ^ (q & 3)) << 3)];
        }

        // PV: wave w owns d-tiles 2w, 2w+1; B-frags reused across q-subtiles
        #pragma unroll
        for (int jj = 0; jj < 2; ++jj) {
            int d = (2 * w + jj) * 16 + lo16;
            int p = d * 32 + ((hi4 ^ ((d >> 1) & 3)) << 3);
            half8 bh  = *(const half8*)&Vl[cur][p];
            half8 b2h = *(const half8*)&V2h[cur][p];
            half8 b2l = *(const half8*)&V2l[cur][p];
            #pragma unroll
            for (int qs = 0; qs < 4; ++qs) {
                accM[qs][jj] = __builtin_amdgcn_mfma_f32_16x16x32_f16(pa[qs], bh,  accM[qs][jj], 0, 0, 0);
                accE[qs][jj] = __builtin_amdgcn_mfma_f32_16x16x32_f16(pa[qs], b2h, accE[qs][jj], 0, 0, 0);
                accE[qs][jj] = __builtin_amdgcn_mfma_f32_16x16x32_f16(pa[qs], b2l, accE[qs][jj], 0, 0, 0);
            }
        }

        __syncthreads();                  // PV reads done: next A may overwrite
        cur ^= 1;
    }

    // ---- l broadcast ----
    if (w < 4) {
        #pragma unroll
        for (int r = 0; r < 4; ++r) {
            float lr = lv[r];
            lr += __shfl_xor(lr, 1);
            lr += __shfl_xor(lr, 2);
            lr += __shfl_xor(lr, 4);
            lr += __shfl_xor(lr, 8);
            if (lo16 == 0) l_lds[w * 16 + hi4 * 4 + r] = lr;
        }
    }
    __syncthreads();

    // ---- fused epilogue ----
    const float* mfc = stats_fcs;
    const float* rfc = stats_fcs + B * D;
    #pragma unroll
    for (int qs = 0; qs < 4; ++qs) {
        #pragma unroll
        for (int r = 0; r < 4; ++r) {
            float linv = 1.f / l_lds[qs * 16 + hi4 * 4 + r];
            int q = q0 + qs * 16 + hi4 * 4 + r;
            size_t rowb = ((size_t)(b * T + q)) * D;
            #pragma unroll
            for (int jj = 0; jj < 2; ++jj) {
                int d = (2 * w + jj) * 16 + lo16;
                float M  = accM[qs][jj][r] * linv;
                float E2 = accE[qs][jj][r] * linv;
                float S  = sqrtf(fmaxf(E2 - M * M, 1e-6f));
                float f  = fcs[rowb + d];
                out[rowb + d] = S * ((f - mfc[b * D + d]) * rfc[b * D + d]) + M;
            }
        }
    }
}

// ---------------------------------------------------------------------------
extern "C" void kernel_launch(void* const* d_in, const int* in_sizes, int n_in,
                              void* d_out, int out_size, void* d_ws, size_t ws_size,
                              hipStream_t stream)
{
    const float* fc  = (const float*)d_in[0];
    const float* fs  = (const float*)d_in[1];
    const float* fcs = (const float*)d_in[2];
    const float* Wf  = (const float*)d_in[3];
    const float* bf  = (const float*)d_in[4];
    const float* Wg  = (const float*)d_in[5];
    const float* bg  = (const float*)d_in[6];
    const float* Wh  = (const float*)d_in[7];
    const float* bh  = (const float*)d_in[8];
    float* out = (float*)d_out;

    char* ws = (char*)d_ws;
    float* stats = (float*)ws;                           // 24 KB
    float* part  = (float*)(ws + (64 << 10));            // 384 KB
    _Float16* Whi = (_Float16*)(ws + (512 << 10));       // 3*128 KB
    _Float16* Wlo = Whi + 3 * 65536;                     // 3*128 KB
    _Float16* Qg   = (_Float16*)(ws + (2 << 20));        // 8 MB each
    _Float16* Kg   = Qg  + (size_t)B * T * D;
    _Float16* Vtg  = Kg  + (size_t)B * T * D;
    _Float16* V2hg = Vtg + (size_t)B * T * D;
    _Float16* V2lg = V2hg + (size_t)B * T * D;

    k_stats_part<<<3 * B * NCH, 256, 0, stream>>>(fc, fs, fcs, part);
    k_stats_final<<<3 * B, 256, 0, stream>>>(part, stats);
    k_wprep<<<3 * 256, 256, 0, stream>>>(Wf, Wg, Wh, Whi, Wlo);

    float* st_fc  = stats + 0 * 2 * B * D;
    float* st_fs  = stats + 1 * 2 * B * D;
    float* st_fcs = stats + 2 * 2 * B * D;

    k_gemm_mfma<<<(B * T) / 64, 256, 0, stream>>>(fc, Whi,             Wlo,             bf, st_fc, 1, 1, Qg, nullptr, nullptr, nullptr);
    k_gemm_mfma<<<(B * T) / 64, 256, 0, stream>>>(fs, Whi + 65536,     Wlo + 65536,     bg, st_fs, 1, 1, Kg, nullptr, nullptr, nullptr);
    k_gemm_mfma<<<(B * T) / 64, 256, 0, stream>>>(fs, Whi + 2 * 65536, Wlo + 2 * 65536, bh, st_fs, 0, 2, nullptr, Vtg, V2hg, V2lg);

    k_attn<<<B * (T / 64), 512, 0, stream>>>(Qg, Kg, Vtg, V2hg, V2lg, fcs, st_fcs, out);
}